// Round 2
// baseline (776.428 us; speedup 1.0000x reference)
//
#include <hip/hip_runtime.h>
#include <hip/hip_bf16.h>
#include <math.h>

// Problem constants
constexpr int B = 32, S = 2048, D = 1024, E = 16, TK = 4, O = 1024;
constexpr int KD = TK * D;       // 4096
constexpr int KS = 8;            // split-K factor for grouped GEMMs

// ---------------------------------------------------------------------------
// K1: gating logits, transposed out: logitsT[b][e][s] = x[b,s,:]·Wg[:,e]+bg[e]
// grid = B*S/64 blocks; 4 waves each own a 256-col slice of D; 8-deep float4
// batching; wave-uniform Wg reads (scalar pipe); LDS cross-wave reduce.
// ---------------------------------------------------------------------------
__global__ __launch_bounds__(256) void k_logits(
    const float* __restrict__ x, const float* __restrict__ Wg,
    const float* __restrict__ bg, float* __restrict__ logitsT) {
  int tid = threadIdx.x;
  int lane = tid & 63;
  int wid = __builtin_amdgcn_readfirstlane(tid >> 6);   // 0..3, wave-uniform
  int row0 = blockIdx.x * 64;
  int row = row0 + lane;                                // global token row
  const float* xr = x + (size_t)row * D + wid * 256;
  const float* wg = Wg + (size_t)wid * 256 * E;         // scalar base
  float acc[E];
#pragma unroll
  for (int e = 0; e < E; e++) acc[e] = 0.f;
  for (int it = 0; it < 64; it += 8) {
    float4 xv[8];
#pragma unroll
    for (int u = 0; u < 8; u++)
      xv[u] = *(const float4*)(xr + (it + u) * 4);
#pragma unroll
    for (int u = 0; u < 8; u++) {
      const float* w0 = wg + (size_t)(it + u) * 4 * E;  // wave-uniform
#pragma unroll
      for (int e = 0; e < E; e++)
        acc[e] += xv[u].x * w0[e] + xv[u].y * w0[E + e] +
                  xv[u].z * w0[2 * E + e] + xv[u].w * w0[3 * E + e];
    }
  }
  __shared__ float red[4][64][17];
#pragma unroll
  for (int e = 0; e < E; e++) red[wid][lane][e] = acc[e];
  __syncthreads();
  int b = row0 >> 11;          // row0 / S
  int s0 = row0 & (S - 1);
#pragma unroll
  for (int i = 0; i < 4; i++) {
    int e = wid + i * 4;       // wave w writes e = w, w+4, w+8, w+12
    float v = red[0][lane][e] + red[1][lane][e] + red[2][lane][e] +
              red[3][lane][e] + bg[e];
    logitsT[((size_t)b * E + e) * S + s0 + lane] = v;   // 256 B coalesced
  }
}

// ---------------------------------------------------------------------------
// K2: per (b,e): softmax-over-tokens denominator + top-4 (value-desc, tie->low idx)
// One block per (b,e).  (unchanged — not a measured bottleneck)
// ---------------------------------------------------------------------------
__global__ __launch_bounds__(256) void k_topk(
    const float* __restrict__ logitsT, int* __restrict__ tIdx,
    float* __restrict__ tVal) {
  int be = blockIdx.x;                       // 0 .. B*E-1
  const float* lrow = logitsT + (size_t)be * S;
  __shared__ float sv[S];
  __shared__ float red[256];
  __shared__ int redi[256];
  int t = threadIdx.x;
  for (int i = t; i < S; i += 256) sv[i] = lrow[i];
  __syncthreads();
  // global max
  float m = -1e30f;
  for (int i = t; i < S; i += 256) m = fmaxf(m, sv[i]);
  red[t] = m;
  __syncthreads();
  for (int off = 128; off > 0; off >>= 1) {
    if (t < off) red[t] = fmaxf(red[t], red[t + off]);
    __syncthreads();
  }
  float gmax = red[0];
  __syncthreads();
  // sum of exp
  float se = 0.f;
  for (int i = t; i < S; i += 256) se += expf(sv[i] - gmax);
  red[t] = se;
  __syncthreads();
  for (int off = 128; off > 0; off >>= 1) {
    if (t < off) red[t] += red[t + off];
    __syncthreads();
  }
  float sumexp = red[0];
  __syncthreads();
  // 4 argmax passes
  for (int j = 0; j < 4; j++) {
    float bv = -1e30f;
    int bi = S;
    for (int i = t; i < S; i += 256) {
      float v = sv[i];
      if (v > bv || (v == bv && i < bi)) { bv = v; bi = i; }
    }
    red[t] = bv;
    redi[t] = bi;
    __syncthreads();
    for (int off = 128; off > 0; off >>= 1) {
      if (t < off) {
        float v2 = red[t + off];
        int i2 = redi[t + off];
        if (v2 > red[t] || (v2 == red[t] && i2 < redi[t])) {
          red[t] = v2;
          redi[t] = i2;
        }
      }
      __syncthreads();
    }
    if (t == 0) {
      tIdx[be * TK + j] = redi[0];
      tVal[be * TK + j] = expf(red[0] - gmax) / sumexp;
      sv[redi[0]] = -1e30f;   // mask for next pass
    }
    __syncthreads();
  }
}

// ---------------------------------------------------------------------------
// K3 (fused gather + layer-1 GEMM partial):
//   part[ks][e][n][m] = vm[m] * sum_{k in chunk} x[m, idx[m,e,j], d0+k] * W1[e][k0+k][n]
// Within a split-K chunk (KC=512), the slot j = ks>>1 is CONSTANT, so the
// gathered A-row is one contiguous 512-float segment of x, wave-uniform ->
// scalar loads. Gate value applied as a per-row scale at store time.
// 512 threads = 8 waves; wave w owns m-rows [4w,4w+4); lane owns 4 n (float4
// W loads -> 1 KB/wave/instr, 8-way shared through L1). 16 waves/CU.
// ---------------------------------------------------------------------------
__global__ __launch_bounds__(512) void k_gemm1(
    const float* __restrict__ x, const int* __restrict__ tIdx,
    const float* __restrict__ tVal, const float* __restrict__ W,
    float* __restrict__ part) {
  int e = blockIdx.x, nt = blockIdx.y, ks = blockIdx.z;
  int tid = threadIdx.x;
  int lane = tid & 63;
  int m0 = __builtin_amdgcn_readfirstlane((tid >> 6) * 4);  // 0,4,...,28
  int n0 = nt * 256 + lane * 4;
  int j = ks >> 1;             // token slot (k block of 1024)
  int d0 = (ks & 1) * 512;     // offset within the slot
  int k0 = ks * 512;           // global k offset into W rows
  const float* xb[4];
  float vm[4];
#pragma unroll
  for (int i = 0; i < 4; i++) {
    int b = m0 + i;                                   // wave-uniform
    int r = tIdx[(b * E + e) * TK + j];
    vm[i] = tVal[(b * E + e) * TK + j];
    xb[i] = x + ((size_t)b * S + r) * D + d0;
  }
  const float* w = W + ((size_t)e * KD + k0) * O + n0;
  float acc[4][4];
#pragma unroll
  for (int i = 0; i < 4; i++)
#pragma unroll
    for (int q = 0; q < 4; q++) acc[i][q] = 0.f;
  for (int k = 0; k < 512; k += 8) {
    float4 wv[8];
#pragma unroll
    for (int u = 0; u < 8; u++)
      wv[u] = *(const float4*)(w + (size_t)(k + u) * O);
#pragma unroll
    for (int u = 0; u < 8; u++) {
#pragma unroll
      for (int i = 0; i < 4; i++) {
        float av = xb[i][k + u];                      // s_load (uniform)
        acc[i][0] += av * wv[u].x;
        acc[i][1] += av * wv[u].y;
        acc[i][2] += av * wv[u].z;
        acc[i][3] += av * wv[u].w;
      }
    }
  }
  float* pb = part + (((size_t)ks * E + e) * O + n0) * 32 + m0;
#pragma unroll
  for (int ni = 0; ni < 4; ni++)
    *(float4*)(pb + ni * 32) =
        make_float4(acc[0][ni] * vm[0], acc[1][ni] * vm[1],
                    acc[2][ni] * vm[2], acc[3][ni] * vm[3]);
}

// ---------------------------------------------------------------------------
// K4: split-K grouped GEMM partial (layers 2/3):
//   part[ks][e][n][m] = sum_k AT[e][k0+k][m] * W[e][k0+k][n]
// Same 512-thread / 8-wave structure as k_gemm1; A from transposed act buffer
// (wave-uniform scalar loads).
// ---------------------------------------------------------------------------
template <int KC>
__global__ __launch_bounds__(512) void k_gemm_part(
    const float* __restrict__ AT,   // [E][Ktot][32]
    const float* __restrict__ W,    // [E][Ktot][O]
    float* __restrict__ part,       // [KS][E][O][32]
    int Ktot) {
  int e = blockIdx.x, nt = blockIdx.y, ks = blockIdx.z;
  int tid = threadIdx.x;
  int lane = tid & 63;
  int m0 = __builtin_amdgcn_readfirstlane((tid >> 6) * 4);  // 0,4,...,28
  int n0 = nt * 256 + lane * 4;
  int k0 = ks * KC;
  const float* a = AT + ((size_t)e * Ktot + k0) * 32 + m0;  // wave-uniform
  const float* w = W + ((size_t)e * Ktot + k0) * O + n0;
  float acc[4][4];
#pragma unroll
  for (int i = 0; i < 4; i++)
#pragma unroll
    for (int q = 0; q < 4; q++) acc[i][q] = 0.f;
  for (int k = 0; k < KC; k += 8) {
    float4 wv[8];
#pragma unroll
    for (int u = 0; u < 8; u++)
      wv[u] = *(const float4*)(w + (size_t)(k + u) * O);
#pragma unroll
    for (int u = 0; u < 8; u++) {
      const float* ar = a + (size_t)(k + u) * 32;           // scalar loads
#pragma unroll
      for (int i = 0; i < 4; i++) {
        float av = ar[i];
        acc[i][0] += av * wv[u].x;
        acc[i][1] += av * wv[u].y;
        acc[i][2] += av * wv[u].z;
        acc[i][3] += av * wv[u].w;
      }
    }
  }
  float* pb = part + (((size_t)ks * E + e) * O + n0) * 32 + m0;
#pragma unroll
  for (int ni = 0; ni < 4; ni++)
    *(float4*)(pb + ni * 32) =
        make_float4(acc[0][ni], acc[1][ni], acc[2][ni], acc[3][ni]);
}

// ---------------------------------------------------------------------------
// K5: reduce split-K partials + bias + optional ReLU -> transposed act layout
//   outT[e][n][m], processed as float4 over m.  (unchanged)
// ---------------------------------------------------------------------------
__global__ __launch_bounds__(256) void k_reduce_act(
    const float* __restrict__ part, const float* __restrict__ bias,
    float* __restrict__ outT, int relu) {
  size_t g = (size_t)blockIdx.x * 256 + threadIdx.x;   // float4 index
  const size_t stride4 = (size_t)E * O * 32 / 4;       // 131072
  const float4* p4 = (const float4*)part;
  float4 s = p4[g];
#pragma unroll
  for (int ks = 1; ks < KS; ks++) {
    float4 v = p4[(size_t)ks * stride4 + g];
    s.x += v.x; s.y += v.y; s.z += v.z; s.w += v.w;
  }
  size_t el = g * 4;
  int n = (int)((el / 32) % O);
  int e = (int)(el / ((size_t)32 * O));
  float bv = bias[e * O + n];
  s.x += bv; s.y += bv; s.z += bv; s.w += bv;
  if (relu) {
    s.x = fmaxf(s.x, 0.f); s.y = fmaxf(s.y, 0.f);
    s.z = fmaxf(s.z, 0.f); s.w = fmaxf(s.w, 0.f);
  }
  ((float4*)outT)[g] = s;
}

// ---------------------------------------------------------------------------
// K6: final reduce + bias, transposed through LDS to d_out[b][e][o]
// (unchanged)
// ---------------------------------------------------------------------------
__global__ __launch_bounds__(256) void k_final(
    const float* __restrict__ part, const float* __restrict__ bias,
    float* __restrict__ out) {
  int e = blockIdx.x;
  int o0 = blockIdx.y * 64;
  __shared__ float sd[64][33];
  int tid = threadIdx.x;
  const size_t stride = (size_t)E * O * 32;
  for (int c = 0; c < 8; c++) {
    int idx = c * 256 + tid;          // 0..2047
    int orel = idx / 32, b = idx % 32;
    size_t off = ((size_t)e * O + o0 + orel) * 32 + b;
    float s = part[off];
#pragma unroll
    for (int ks = 1; ks < KS; ks++) s += part[(size_t)ks * stride + off];
    sd[orel][b] = s + bias[e * O + o0 + orel];
  }
  __syncthreads();
  for (int c = 0; c < 8; c++) {
    int idx = c * 256 + tid;
    int b = idx / 64, orr = idx % 64;
    out[((size_t)b * E + e) * O + o0 + orr] = sd[orr][b];
  }
}

// ---------------------------------------------------------------------------
extern "C" void kernel_launch(void* const* d_in, const int* in_sizes, int n_in,
                              void* d_out, int out_size, void* d_ws,
                              size_t ws_size, hipStream_t stream) {
  (void)in_sizes; (void)n_in; (void)out_size; (void)ws_size;
  const float* x  = (const float*)d_in[0];
  const float* Wg = (const float*)d_in[1];
  const float* bg = (const float*)d_in[2];
  const float* W1 = (const float*)d_in[3];
  const float* b1 = (const float*)d_in[4];
  const float* W2 = (const float*)d_in[5];
  const float* b2 = (const float*)d_in[6];
  const float* W3 = (const float*)d_in[7];
  const float* b3 = (const float*)d_in[8];
  float* out = (float*)d_out;

  char* ws = (char*)d_ws;
  float* logitsT = (float*)ws;                                   // 4 MB
  int*   tIdx    = (int*)(ws + (4u << 20));                      // 8 KB
  float* tVal    = (float*)(ws + (4u << 20) + (8u << 10));       // 8 KB
  float* part    = (float*)(ws + (12u << 20) + (64u << 10));     // 16 MB
  float* h1T     = (float*)(ws + (28u << 20) + (64u << 10));     // 2 MB
  float* h2T     = (float*)(ws + (30u << 20) + (64u << 10));     // 2 MB

  // 1) gating logits (transposed [B,E,S])
  k_logits<<<B * S / 64, 256, 0, stream>>>(x, Wg, bg, logitsT);
  // 2) softmax-over-tokens + top-4 per (b,e)
  k_topk<<<B * E, 256, 0, stream>>>(logitsT, tIdx, tVal);
  // 3) layer 1 fused gather+GEMM: [32,4096] @ W1[e] -> part
  k_gemm1<<<dim3(E, O / 256, KS), 512, 0, stream>>>(x, tIdx, tVal, W1, part);
  k_reduce_act<<<(E * O * 32 / 4) / 256, 256, 0, stream>>>(part, b1, h1T, 1);
  // 4) layer 2
  k_gemm_part<O / KS><<<dim3(E, O / 256, KS), 512, 0, stream>>>(h1T, W2, part, O);
  k_reduce_act<<<(E * O * 32 / 4) / 256, 256, 0, stream>>>(part, b2, h2T, 1);
  // 5) layer 3 + transpose to [B,E,O]
  k_gemm_part<O / KS><<<dim3(E, O / 256, KS), 512, 0, stream>>>(h2T, W3, part, O);
  k_final<<<dim3(E, O / 64), 256, 0, stream>>>(part, b3, out);
}